// Round 1
// baseline (2656.941 us; speedup 1.0000x reference)
//
#include <hip/hip_runtime.h>
#include <math.h>

#define TB 16
#define TT 8192
#define TM 128
#define ED 512     // EMBED_DIM
#define QD 256     // QUANT_DIM
#define QN 1024    // QUANT_N
#define HH 512     // T/16
#define WW 8       // M/16
#define NTOK (TB*HH*WW)   // 65536

#define PSTR 260   // patch LDS stride (words), 260%32==4 -> <=2-way conflicts
#define FSTR 516   // normalized-feats LDS stride
#define TSTR 260   // t-tile LDS stride in argmax kernel

// ---------------- kernel 1: codebook row l2-normalize ----------------
__global__ __launch_bounds__(64) void k_cbnorm(const float* __restrict__ cb,
                                               float* __restrict__ cbn) {
    int k = blockIdx.x;
    int lane = threadIdx.x;               // 64 lanes, 4 floats each = 256
    float4 v = ((const float4*)(cb + (size_t)k * QD))[lane];
    float ss = v.x*v.x + v.y*v.y + v.z*v.z + v.w*v.w;
    #pragma unroll
    for (int off = 32; off > 0; off >>= 1) ss += __shfl_down(ss, off);
    ss = __shfl(ss, 0);
    float inv = 1.0f / fmaxf(sqrtf(ss), 1e-12f);
    float4 o; o.x = v.x*inv; o.y = v.y*inv; o.z = v.z*inv; o.w = v.w*inv;
    ((float4*)(cbn + (size_t)k * QD))[lane] = o;
}

// ---------------- kernel 2: proj (512x256) -> projT (256x512) ----------------
__global__ __launch_bounds__(256) void k_transpose(const float* __restrict__ proj,
                                                   float* __restrict__ projT) {
    int idx = blockIdx.x * 256 + threadIdx.x;   // 131072 total
    int d = idx >> 8, q = idx & 255;
    projT[q * ED + d] = proj[idx];
}

// ---------------- kernel 3: fused conv + LN + proj -> t[65536][256] ----------------
__global__ __launch_bounds__(256) void k_feat(const float* __restrict__ fbank,
                                              const float* __restrict__ convw,
                                              const float* __restrict__ projT,
                                              float* __restrict__ tws) {
    __shared__ float sbuf[16 * FSTR];   // phase A: patches (stride PSTR); phase B: ln-feats (stride FSTR)
    __shared__ float psum[64][16];
    __shared__ float psq[64][16];
    __shared__ float muL[16], rsL[16];

    int t = threadIdx.x;
    int n0 = blockIdx.x * 16;

    // ---- load 16 patches (16x256) into LDS ----
    {
        int j = t >> 4, ph = t & 15;
        int n = n0 + j;
        int b = n >> 12, r = n & 4095, h = r >> 3, w = r & 7;
        const float4* src = (const float4*)(fbank + ((size_t)(b * TT + h * 16 + ph)) * TM + w * 16);
        float4* dst = (float4*)&sbuf[j * PSTR + ph * 16];
        #pragma unroll
        for (int c = 0; c < 4; ++c) dst[c] = src[c];
    }
    __syncthreads();

    // ---- stage 1: feats[16][512] = patch @ conv_w^T, register tile 4 tokens x 8 dims ----
    int tg  = t & 3;        // tokens {tg, tg+4, tg+8, tg+12}
    int dgr = t >> 2;       // dims dgr*8 .. dgr*8+7
    float acc[4][8];
    #pragma unroll
    for (int u = 0; u < 4; ++u)
        #pragma unroll
        for (int i = 0; i < 8; ++i) acc[u][i] = 0.f;

    const float* wbase = convw + (size_t)dgr * 8 * QD;
    for (int kc = 0; kc < 64; ++kc) {
        float4 p[4];
        #pragma unroll
        for (int u = 0; u < 4; ++u)
            p[u] = *(const float4*)&sbuf[(tg + 4*u) * PSTR + kc * 4];
        #pragma unroll
        for (int i = 0; i < 8; ++i) {
            float4 wv = *(const float4*)(wbase + i * QD + kc * 4);
            #pragma unroll
            for (int u = 0; u < 4; ++u) {
                acc[u][i] += p[u].x * wv.x;
                acc[u][i] += p[u].y * wv.y;
                acc[u][i] += p[u].z * wv.z;
                acc[u][i] += p[u].w * wv.w;
            }
        }
    }
    __syncthreads();   // all patch reads done before sbuf is reused

    // ---- LayerNorm statistics ----
    #pragma unroll
    for (int u = 0; u < 4; ++u) {
        float s = 0.f, q2 = 0.f;
        #pragma unroll
        for (int i = 0; i < 8; ++i) { s += acc[u][i]; q2 += acc[u][i] * acc[u][i]; }
        psum[dgr][tg + 4*u] = s;
        psq [dgr][tg + 4*u] = q2;
    }
    __syncthreads();
    if (t < 16) {
        float s = 0.f, q2 = 0.f;
        for (int g = 0; g < 64; ++g) { s += psum[g][t]; q2 += psq[g][t]; }
        float mu  = s  * (1.0f / 512.0f);
        float var = q2 * (1.0f / 512.0f) - mu * mu;
        muL[t] = mu;
        rsL[t] = rsqrtf(var + 1e-5f);   // pure positive scale: argmax-neutral, approx ok
    }
    __syncthreads();

    // ---- write normalized feats into sbuf (stride FSTR) ----
    #pragma unroll
    for (int u = 0; u < 4; ++u) {
        int j = tg + 4*u;
        float mu = muL[j], rs = rsL[j];
        float4 o0, o1;
        o0.x = (acc[u][0]-mu)*rs; o0.y = (acc[u][1]-mu)*rs;
        o0.z = (acc[u][2]-mu)*rs; o0.w = (acc[u][3]-mu)*rs;
        o1.x = (acc[u][4]-mu)*rs; o1.y = (acc[u][5]-mu)*rs;
        o1.z = (acc[u][6]-mu)*rs; o1.w = (acc[u][7]-mu)*rs;
        *(float4*)&sbuf[j * FSTR + dgr * 8]     = o0;
        *(float4*)&sbuf[j * FSTR + dgr * 8 + 4] = o1;
    }
    __syncthreads();

    // ---- stage 2: t[16][256] = ln_feats @ proj, register tile 4 tokens x 4 q ----
    int qg = t >> 2;        // q = qg*4 .. qg*4+3
    float a2[4][4];
    #pragma unroll
    for (int u = 0; u < 4; ++u)
        #pragma unroll
        for (int qq = 0; qq < 4; ++qq) a2[u][qq] = 0.f;

    const float* pb = projT + (size_t)qg * 4 * ED;
    for (int dc = 0; dc < 128; ++dc) {
        float4 f[4];
        #pragma unroll
        for (int u = 0; u < 4; ++u)
            f[u] = *(const float4*)&sbuf[(tg + 4*u) * FSTR + dc * 4];
        #pragma unroll
        for (int qq = 0; qq < 4; ++qq) {
            float4 pv = *(const float4*)(pb + qq * ED + dc * 4);
            #pragma unroll
            for (int u = 0; u < 4; ++u) {
                a2[u][qq] += f[u].x * pv.x;
                a2[u][qq] += f[u].y * pv.y;
                a2[u][qq] += f[u].z * pv.z;
                a2[u][qq] += f[u].w * pv.w;
            }
        }
    }
    #pragma unroll
    for (int u = 0; u < 4; ++u) {
        int j = tg + 4*u;
        float4 o = make_float4(a2[u][0], a2[u][1], a2[u][2], a2[u][3]);
        *(float4*)(tws + (size_t)(n0 + j) * QD + qg * 4) = o;
    }
}

// ---------------- kernel 4: sim = t @ cbn^T, argmax over 1024 codes ----------------
__global__ __launch_bounds__(256) void k_argmax(const float* __restrict__ tws,
                                                const float* __restrict__ cbn,
                                                int* __restrict__ out) {
    __shared__ float tl[32 * TSTR];
    __shared__ float rv[8][32];
    __shared__ int   ri[8][32];
    int t = threadIdx.x;
    int n0 = blockIdx.x * 32;

    // ---- load 32 token rows of t into LDS ----
    {
        int j = t >> 3, part = t & 7;
        const float4* src = (const float4*)(tws + (size_t)(n0 + j) * QD) + part * 8;
        float4* dst = (float4*)&tl[j * TSTR + part * 32];
        #pragma unroll
        for (int c = 0; c < 8; ++c) dst[c] = src[c];
    }
    __syncthreads();

    int j = t & 31, kg = t >> 5;          // this thread: token j, codes kg*128..kg*128+127
    float bv = -3.4e38f; int bi = 0;
    const float* tj = &tl[j * TSTR];
    for (int g = 0; g < 8; ++g) {
        int kb = kg * 128 + g * 16;
        float a[16];
        #pragma unroll
        for (int c = 0; c < 16; ++c) a[c] = 0.f;
        const float* cb0 = cbn + (size_t)kb * QD;
        for (int dc = 0; dc < 64; ++dc) {
            float4 tv = *(const float4*)&tj[dc * 4];
            #pragma unroll
            for (int c = 0; c < 16; ++c) {
                float4 cv = *(const float4*)(cb0 + c * QD + dc * 4);
                a[c] += tv.x * cv.x;
                a[c] += tv.y * cv.y;
                a[c] += tv.z * cv.z;
                a[c] += tv.w * cv.w;
            }
        }
        #pragma unroll
        for (int c = 0; c < 16; ++c) {      // ascending k, strict > : first-max tie-break
            if (a[c] > bv) { bv = a[c]; bi = kb + c; }
        }
    }
    rv[kg][j] = bv; ri[kg][j] = bi;
    __syncthreads();
    if (t < 32) {
        float best = rv[0][t]; int besti = ri[0][t];
        #pragma unroll
        for (int g = 1; g < 8; ++g) {       // ascending kg: keeps lowest index on tie
            if (rv[g][t] > best) { best = rv[g][t]; besti = ri[g][t]; }
        }
        out[n0 + t] = besti;
    }
}

extern "C" void kernel_launch(void* const* d_in, const int* in_sizes, int n_in,
                              void* d_out, int out_size, void* d_ws, size_t ws_size,
                              hipStream_t stream) {
    const float* fbank = (const float*)d_in[0];   // 16 x 8192 x 128
    const float* convw = (const float*)d_in[1];   // 512 x 1 x 16 x 16
    const float* proj  = (const float*)d_in[2];   // 512 x 256
    const float* cbook = (const float*)d_in[3];   // 1024 x 256
    int* out = (int*)d_out;                       // 65536 int32

    char* ws = (char*)d_ws;
    float* cbn   = (float*)ws;                              // 1 MB
    float* projT = (float*)(ws + (1u << 20));               // 512 KB
    float* tws   = (float*)(ws + (1u << 20) + (1u << 19));  // 64 MB

    hipLaunchKernelGGL(k_cbnorm,    dim3(QN),            dim3(64),  0, stream, cbook, cbn);
    hipLaunchKernelGGL(k_transpose, dim3(ED * QD / 256), dim3(256), 0, stream, proj, projT);
    hipLaunchKernelGGL(k_feat,      dim3(NTOK / 16),     dim3(256), 0, stream, fbank, convw, projT, tws);
    hipLaunchKernelGGL(k_argmax,    dim3(NTOK / 32),     dim3(256), 0, stream, tws, cbn, out);
}

// Round 2
// 1996.880 us; speedup vs baseline: 1.3305x; 1.3305x over previous
//
#include <hip/hip_runtime.h>
#include <math.h>

#define TB 16
#define TT 8192
#define TM 128
#define ED 512     // EMBED_DIM
#define QD 256     // QUANT_DIM
#define QN 1024    // QUANT_N
#define HH 512     // T/16
#define WW 8       // M/16
#define NTOK (TB*HH*WW)   // 65536

#define PSTR 260   // patch LDS stride (words), 260%32==4 -> <=2-way conflicts
#define FSTR 516   // normalized-feats LDS stride

// ---------------- kernel 1: codebook row l2-normalize ----------------
__global__ __launch_bounds__(64) void k_cbnorm(const float* __restrict__ cb,
                                               float* __restrict__ cbn) {
    int k = blockIdx.x;
    int lane = threadIdx.x;               // 64 lanes, 4 floats each = 256
    float4 v = ((const float4*)(cb + (size_t)k * QD))[lane];
    float ss = v.x*v.x + v.y*v.y + v.z*v.z + v.w*v.w;
    #pragma unroll
    for (int off = 32; off > 0; off >>= 1) ss += __shfl_down(ss, off);
    ss = __shfl(ss, 0);
    float inv = 1.0f / fmaxf(sqrtf(ss), 1e-12f);
    float4 o; o.x = v.x*inv; o.y = v.y*inv; o.z = v.z*inv; o.w = v.w*inv;
    ((float4*)(cbn + (size_t)k * QD))[lane] = o;
}

// ---------------- kernel 2: proj (512x256) -> projT (256x512) ----------------
__global__ __launch_bounds__(256) void k_transpose(const float* __restrict__ proj,
                                                   float* __restrict__ projT) {
    int idx = blockIdx.x * 256 + threadIdx.x;   // 131072 total
    int d = idx >> 8, q = idx & 255;
    projT[q * ED + d] = proj[idx];
}

// ---------------- kernel 3: fused conv + LN + proj -> t[65536][256] ----------------
__global__ __launch_bounds__(256) void k_feat(const float* __restrict__ fbank,
                                              const float* __restrict__ convw,
                                              const float* __restrict__ projT,
                                              float* __restrict__ tws) {
    __shared__ float sbuf[16 * FSTR];   // phase A: patches (stride PSTR); phase B: ln-feats (stride FSTR)
    __shared__ float psum[64][16];
    __shared__ float psq[64][16];
    __shared__ float muL[16], rsL[16];

    int t = threadIdx.x;
    int n0 = blockIdx.x * 16;

    // ---- load 16 patches (16x256) into LDS ----
    {
        int j = t >> 4, ph = t & 15;
        int n = n0 + j;
        int b = n >> 12, r = n & 4095, h = r >> 3, w = r & 7;
        const float4* src = (const float4*)(fbank + ((size_t)(b * TT + h * 16 + ph)) * TM + w * 16);
        float4* dst = (float4*)&sbuf[j * PSTR + ph * 16];
        #pragma unroll
        for (int c = 0; c < 4; ++c) dst[c] = src[c];
    }
    __syncthreads();

    // ---- stage 1: feats[16][512] = patch @ conv_w^T, register tile 4 tokens x 8 dims ----
    int tg  = t & 3;        // tokens {tg, tg+4, tg+8, tg+12}
    int dgr = t >> 2;       // dims dgr*8 .. dgr*8+7
    float acc[4][8];
    #pragma unroll
    for (int u = 0; u < 4; ++u)
        #pragma unroll
        for (int i = 0; i < 8; ++i) acc[u][i] = 0.f;

    const float* wbase = convw + (size_t)dgr * 8 * QD;
    for (int kc = 0; kc < 64; ++kc) {
        float4 p[4];
        #pragma unroll
        for (int u = 0; u < 4; ++u)
            p[u] = *(const float4*)&sbuf[(tg + 4*u) * PSTR + kc * 4];
        #pragma unroll
        for (int i = 0; i < 8; ++i) {
            float4 wv = *(const float4*)(wbase + i * QD + kc * 4);
            #pragma unroll
            for (int u = 0; u < 4; ++u) {
                acc[u][i] += p[u].x * wv.x;
                acc[u][i] += p[u].y * wv.y;
                acc[u][i] += p[u].z * wv.z;
                acc[u][i] += p[u].w * wv.w;
            }
        }
    }
    __syncthreads();   // all patch reads done before sbuf is reused

    // ---- LayerNorm statistics ----
    #pragma unroll
    for (int u = 0; u < 4; ++u) {
        float s = 0.f, q2 = 0.f;
        #pragma unroll
        for (int i = 0; i < 8; ++i) { s += acc[u][i]; q2 += acc[u][i] * acc[u][i]; }
        psum[dgr][tg + 4*u] = s;
        psq [dgr][tg + 4*u] = q2;
    }
    __syncthreads();
    if (t < 16) {
        float s = 0.f, q2 = 0.f;
        for (int g = 0; g < 64; ++g) { s += psum[g][t]; q2 += psq[g][t]; }
        float mu  = s  * (1.0f / 512.0f);
        float var = q2 * (1.0f / 512.0f) - mu * mu;
        muL[t] = mu;
        rsL[t] = rsqrtf(var + 1e-5f);   // pure positive scale: argmax-neutral, approx ok
    }
    __syncthreads();

    // ---- write normalized feats into sbuf (stride FSTR) ----
    #pragma unroll
    for (int u = 0; u < 4; ++u) {
        int j = tg + 4*u;
        float mu = muL[j], rs = rsL[j];
        float4 o0, o1;
        o0.x = (acc[u][0]-mu)*rs; o0.y = (acc[u][1]-mu)*rs;
        o0.z = (acc[u][2]-mu)*rs; o0.w = (acc[u][3]-mu)*rs;
        o1.x = (acc[u][4]-mu)*rs; o1.y = (acc[u][5]-mu)*rs;
        o1.z = (acc[u][6]-mu)*rs; o1.w = (acc[u][7]-mu)*rs;
        *(float4*)&sbuf[j * FSTR + dgr * 8]     = o0;
        *(float4*)&sbuf[j * FSTR + dgr * 8 + 4] = o1;
    }
    __syncthreads();

    // ---- stage 2: t[16][256] = ln_feats @ proj, register tile 4 tokens x 4 q ----
    int qg = t >> 2;        // q = qg*4 .. qg*4+3
    float a2[4][4];
    #pragma unroll
    for (int u = 0; u < 4; ++u)
        #pragma unroll
        for (int qq = 0; qq < 4; ++qq) a2[u][qq] = 0.f;

    const float* pb = projT + (size_t)qg * 4 * ED;
    for (int dc = 0; dc < 128; ++dc) {
        float4 f[4];
        #pragma unroll
        for (int u = 0; u < 4; ++u)
            f[u] = *(const float4*)&sbuf[(tg + 4*u) * FSTR + dc * 4];
        #pragma unroll
        for (int qq = 0; qq < 4; ++qq) {
            float4 pv = *(const float4*)(pb + qq * ED + dc * 4);
            #pragma unroll
            for (int u = 0; u < 4; ++u) {
                a2[u][qq] += f[u].x * pv.x;
                a2[u][qq] += f[u].y * pv.y;
                a2[u][qq] += f[u].z * pv.z;
                a2[u][qq] += f[u].w * pv.w;
            }
        }
    }
    #pragma unroll
    for (int u = 0; u < 4; ++u) {
        int j = tg + 4*u;
        float4 o = make_float4(a2[u][0], a2[u][1], a2[u][2], a2[u][3]);
        *(float4*)(tws + (size_t)(n0 + j) * QD + qg * 4) = o;
    }
}

// ---------------- kernel 4: sim = t @ cbn^T with LDS-tiled GEMM, argmax over 1024 codes ----------------
// Block: 256 threads, 32 tokens, all 1024 codes in 4 chunks of 256.
// Thread tile: 4 tokens x 8 codes. Ts stride 260 (broadcast reads); Cs stride 36
// (36%32==4 -> lane-adjacent code rows spread across bank quads; 36*4B is 16B-aligned).
#define ATOK 32
#define CCHUNK 256
#define KCH 32
#define CSTR 36
#define TSTR 260

__global__ __launch_bounds__(256) void k_argmax(const float* __restrict__ tws,
                                                const float* __restrict__ cbn,
                                                int* __restrict__ out) {
    __shared__ float Ts[ATOK * TSTR];     // 33.3 KB, full K=256 per token
    __shared__ float Cs[CCHUNK * CSTR];   // 36.9 KB, 256 codes x 32-K slice

    int tid = threadIdx.x;
    int n0 = blockIdx.x * ATOK;

    // ---- stage Ts: 32 rows x 256 floats; 8 threads/row, 128B contiguous per thread ----
    {
        int r = tid >> 3, pp = tid & 7;   // r: 0..31 row, pp: which 128B chunk
        const float4* src = (const float4*)(tws + (size_t)(n0 + r) * QD) + pp * 8;
        float4* dst = (float4*)&Ts[r * TSTR + pp * 32];
        #pragma unroll
        for (int i = 0; i < 8; ++i) dst[i] = src[i];
    }

    int tg = tid >> 5;        // 0..7: tokens {tg, tg+8, tg+16, tg+24}
    int cg = tid & 31;        // 0..31: codes {cg+32j, j=0..7} within chunk

    float best[4]; int bidx[4];
    #pragma unroll
    for (int u = 0; u < 4; ++u) { best[u] = -3.4e38f; bidx[u] = 0; }

    for (int chunk = 0; chunk < QN / CCHUNK; ++chunk) {
        float acc[4][8];
        #pragma unroll
        for (int u = 0; u < 4; ++u)
            #pragma unroll
            for (int j = 0; j < 8; ++j) acc[u][j] = 0.f;

        for (int kc = 0; kc < QD / KCH; ++kc) {
            __syncthreads();
            // ---- stage Cs: 256 codes x 32-K slice; 8 passes of 32 rows ----
            {
                int r = tid >> 3, pp = tid & 7;
                #pragma unroll
                for (int p = 0; p < 8; ++p) {
                    int row = r + p * 32;
                    float4 v = *(const float4*)(cbn + (size_t)(chunk * CCHUNK + row) * QD
                                                + kc * KCH + pp * 4);
                    *(float4*)&Cs[row * CSTR + pp * 4] = v;
                }
            }
            __syncthreads();

            int k0 = kc * KCH;
            #pragma unroll
            for (int kq = 0; kq < KCH; kq += 4) {
                float4 tv[4];
                #pragma unroll
                for (int u = 0; u < 4; ++u)
                    tv[u] = *(const float4*)&Ts[(tg + 8*u) * TSTR + k0 + kq];
                float4 cv[8];
                #pragma unroll
                for (int j = 0; j < 8; ++j)
                    cv[j] = *(const float4*)&Cs[(cg + 32*j) * CSTR + kq];
                #pragma unroll
                for (int j = 0; j < 8; ++j) {
                    #pragma unroll
                    for (int u = 0; u < 4; ++u) {
                        acc[u][j] += tv[u].x * cv[j].x;
                        acc[u][j] += tv[u].y * cv[j].y;
                        acc[u][j] += tv[u].z * cv[j].z;
                        acc[u][j] += tv[u].w * cv[j].w;
                    }
                }
            }
        }
        // ---- fold chunk into running per-thread argmax (ascending code index, strict >) ----
        #pragma unroll
        for (int j = 0; j < 8; ++j) {
            int code = chunk * CCHUNK + 32 * j + cg;
            #pragma unroll
            for (int u = 0; u < 4; ++u) {
                if (acc[u][j] > best[u]) { best[u] = acc[u][j]; bidx[u] = code; }
            }
        }
    }

    // ---- half-wave reduction over the 32 threads sharing this token set ----
    #pragma unroll
    for (int off = 16; off > 0; off >>= 1) {
        #pragma unroll
        for (int u = 0; u < 4; ++u) {
            float ov = __shfl_down(best[u], off);
            int   oi = __shfl_down(bidx[u], off);
            if (ov > best[u] || (ov == best[u] && oi < bidx[u])) {
                best[u] = ov; bidx[u] = oi;
            }
        }
    }
    if (cg == 0) {
        #pragma unroll
        for (int u = 0; u < 4; ++u) out[n0 + tg + 8*u] = bidx[u];
    }
}

extern "C" void kernel_launch(void* const* d_in, const int* in_sizes, int n_in,
                              void* d_out, int out_size, void* d_ws, size_t ws_size,
                              hipStream_t stream) {
    const float* fbank = (const float*)d_in[0];   // 16 x 8192 x 128
    const float* convw = (const float*)d_in[1];   // 512 x 1 x 16 x 16
    const float* proj  = (const float*)d_in[2];   // 512 x 256
    const float* cbook = (const float*)d_in[3];   // 1024 x 256
    int* out = (int*)d_out;                       // 65536 int32

    char* ws = (char*)d_ws;
    float* cbn   = (float*)ws;                              // 1 MB
    float* projT = (float*)(ws + (1u << 20));               // 512 KB
    float* tws   = (float*)(ws + (1u << 20) + (1u << 19));  // 64 MB

    hipLaunchKernelGGL(k_cbnorm,    dim3(QN),            dim3(64),  0, stream, cbook, cbn);
    hipLaunchKernelGGL(k_transpose, dim3(ED * QD / 256), dim3(256), 0, stream, proj, projT);
    hipLaunchKernelGGL(k_feat,      dim3(NTOK / 16),     dim3(256), 0, stream, fbank, convw, projT, tws);
    hipLaunchKernelGGL(k_argmax,    dim3(NTOK / ATOK),   dim3(256), 0, stream, tws, cbn, out);
}

// Round 4
// 1390.162 us; speedup vs baseline: 1.9112x; 1.4364x over previous
//
#include <hip/hip_runtime.h>
#include <math.h>

#define TB 16
#define TT 8192
#define TM 128
#define ED 512     // EMBED_DIM
#define QD 256     // QUANT_DIM
#define QN 1024    // QUANT_N
#define NTOK 65536

#define PSTR 260   // patch LDS stride (words) in k_feat
#define FSTR 516   // normalized-feats LDS stride in k_feat

// ---------------- kernel 1: codebook l2-normalize -> quad-interleaved cbq ----------------
// cbq layout: [QD/4 quads][QN codes][4 floats]; lane's float4 IS its k-quad.
__global__ __launch_bounds__(64) void k_cbnorm(const float* __restrict__ cb,
                                               float4* __restrict__ cbq) {
    int k = blockIdx.x;
    int lane = threadIdx.x;               // 64 lanes, one k-quad each
    float4 v = ((const float4*)(cb + (size_t)k * QD))[lane];
    float ss = v.x*v.x + v.y*v.y + v.z*v.z + v.w*v.w;
    #pragma unroll
    for (int off = 32; off > 0; off >>= 1) ss += __shfl_down(ss, off);
    ss = __shfl(ss, 0);
    float inv = 1.0f / fmaxf(sqrtf(ss), 1e-12f);
    float4 o; o.x = v.x*inv; o.y = v.y*inv; o.z = v.z*inv; o.w = v.w*inv;
    cbq[(size_t)lane * QN + k] = o;
}

// ---------------- kernel 2: proj (512x256) -> projT (256x512) ----------------
__global__ __launch_bounds__(256) void k_transpose(const float* __restrict__ proj,
                                                   float* __restrict__ projT) {
    int idx = blockIdx.x * 256 + threadIdx.x;   // 131072 total
    int d = idx >> 8, q = idx & 255;
    projT[q * ED + d] = proj[idx];
}

// ---------------- kernel 3: fused conv + LN + proj -> t[65536][256] ----------------
__global__ __launch_bounds__(256) void k_feat(const float* __restrict__ fbank,
                                              const float* __restrict__ convw,
                                              const float* __restrict__ projT,
                                              float* __restrict__ tws) {
    __shared__ float sbuf[16 * FSTR];
    __shared__ float psum[64][16];
    __shared__ float psq[64][16];
    __shared__ float muL[16], rsL[16];

    int t = threadIdx.x;
    int n0 = blockIdx.x * 16;

    {
        int j = t >> 4, ph = t & 15;
        int n = n0 + j;
        int b = n >> 12, r = n & 4095, h = r >> 3, w = r & 7;
        const float4* src = (const float4*)(fbank + ((size_t)(b * TT + h * 16 + ph)) * TM + w * 16);
        float4* dst = (float4*)&sbuf[j * PSTR + ph * 16];
        #pragma unroll
        for (int c = 0; c < 4; ++c) dst[c] = src[c];
    }
    __syncthreads();

    int tg  = t & 3;
    int dgr = t >> 2;
    float acc[4][8];
    #pragma unroll
    for (int u = 0; u < 4; ++u)
        #pragma unroll
        for (int i = 0; i < 8; ++i) acc[u][i] = 0.f;

    const float* wbase = convw + (size_t)dgr * 8 * QD;
    for (int kc = 0; kc < 64; ++kc) {
        float4 p[4];
        #pragma unroll
        for (int u = 0; u < 4; ++u)
            p[u] = *(const float4*)&sbuf[(tg + 4*u) * PSTR + kc * 4];
        #pragma unroll
        for (int i = 0; i < 8; ++i) {
            float4 wv = *(const float4*)(wbase + i * QD + kc * 4);
            #pragma unroll
            for (int u = 0; u < 4; ++u) {
                acc[u][i] += p[u].x * wv.x;
                acc[u][i] += p[u].y * wv.y;
                acc[u][i] += p[u].z * wv.z;
                acc[u][i] += p[u].w * wv.w;
            }
        }
    }
    __syncthreads();

    #pragma unroll
    for (int u = 0; u < 4; ++u) {
        float s = 0.f, q2 = 0.f;
        #pragma unroll
        for (int i = 0; i < 8; ++i) { s += acc[u][i]; q2 += acc[u][i] * acc[u][i]; }
        psum[dgr][tg + 4*u] = s;
        psq [dgr][tg + 4*u] = q2;
    }
    __syncthreads();
    if (t < 16) {
        float s = 0.f, q2 = 0.f;
        for (int g = 0; g < 64; ++g) { s += psum[g][t]; q2 += psq[g][t]; }
        float mu  = s  * (1.0f / 512.0f);
        float var = q2 * (1.0f / 512.0f) - mu * mu;
        muL[t] = mu;
        rsL[t] = rsqrtf(var + 1e-5f);
    }
    __syncthreads();

    #pragma unroll
    for (int u = 0; u < 4; ++u) {
        int j = tg + 4*u;
        float mu = muL[j], rs = rsL[j];
        float4 o0, o1;
        o0.x = (acc[u][0]-mu)*rs; o0.y = (acc[u][1]-mu)*rs;
        o0.z = (acc[u][2]-mu)*rs; o0.w = (acc[u][3]-mu)*rs;
        o1.x = (acc[u][4]-mu)*rs; o1.y = (acc[u][5]-mu)*rs;
        o1.z = (acc[u][6]-mu)*rs; o1.w = (acc[u][7]-mu)*rs;
        *(float4*)&sbuf[j * FSTR + dgr * 8]     = o0;
        *(float4*)&sbuf[j * FSTR + dgr * 8 + 4] = o1;
    }
    __syncthreads();

    int qg = t >> 2;
    float a2[4][4];
    #pragma unroll
    for (int u = 0; u < 4; ++u)
        #pragma unroll
        for (int qq = 0; qq < 4; ++qq) a2[u][qq] = 0.f;

    const float* pb = projT + (size_t)qg * 4 * ED;
    for (int dc = 0; dc < 128; ++dc) {
        float4 f[4];
        #pragma unroll
        for (int u = 0; u < 4; ++u)
            f[u] = *(const float4*)&sbuf[(tg + 4*u) * FSTR + dc * 4];
        #pragma unroll
        for (int qq = 0; qq < 4; ++qq) {
            float4 pv = *(const float4*)(pb + qq * ED + dc * 4);
            #pragma unroll
            for (int u = 0; u < 4; ++u) {
                a2[u][qq] += f[u].x * pv.x;
                a2[u][qq] += f[u].y * pv.y;
                a2[u][qq] += f[u].z * pv.z;
                a2[u][qq] += f[u].w * pv.w;
            }
        }
    }
    #pragma unroll
    for (int u = 0; u < 4; ++u) {
        int j = tg + 4*u;
        float4 o = make_float4(a2[u][0], a2[u][1], a2[u][2], a2[u][3]);
        *(float4*)(tws + (size_t)(n0 + j) * QD + qg * 4) = o;
    }
}

// ---------------- kernel 4: sim = t @ cbn^T, argmax over 1024 codes ----------------
// ATOK=48 tokens/block, 2 chunks of 512 codes, K staged 8-wide (2 quads).
// Thread tile: 6 tokens x 16 codes. All LDS strided accesses are canonical
// lane-contiguous (base + lane*16B); token reads are wave-broadcast.
#define ATOK 48
#define TSTR2 260

__global__ __launch_bounds__(256, 2) void k_argmax(const float* __restrict__ tws,
                                                   const float4* __restrict__ cbq,
                                                   int* __restrict__ out) {
    __shared__ float  Ts[ATOK * TSTR2];   // 49.9 KB
    __shared__ float4 Cs[2][512];         // 16 KB: [k-quad][code][4]

    int tid = threadIdx.x;
    int n0 = blockIdx.x * ATOK;

    // ---- stage Ts: 48 rows x 64 float4 = 3072 float4; 12 per thread ----
    {
        const float4* twsf4 = (const float4*)tws;
        #pragma unroll
        for (int i = 0; i < 12; ++i) {
            int ft = tid + 256 * i;
            int row = ft >> 6, col = ft & 63;
            int grow = n0 + row; if (grow > NTOK - 1) grow = NTOK - 1;
            float4 v = twsf4[(size_t)grow * (QD/4) + col];
            *(float4*)&Ts[row * TSTR2 + col * 4] = v;
        }
    }
    // (first __syncthreads inside the loop publishes Ts before any compute)

    int tg = tid >> 5;       // 0..7: tokens {tg + 8u, u=0..5}
    int cg = tid & 31;       // codes {cg + 32j, j=0..15} within chunk
    int qloc = tid >> 7;     // 0..1: which k-quad this thread stages
    int cidx = tid & 127;    // staging code base

    float best[6]; int bidx[6];
    #pragma unroll
    for (int u = 0; u < 6; ++u) { best[u] = -3.4e38f; bidx[u] = 0; }

    for (int chunk = 0; chunk < 2; ++chunk) {
        float acc[6][16];
        #pragma unroll
        for (int u = 0; u < 6; ++u)
            #pragma unroll
            for (int j = 0; j < 16; ++j) acc[u][j] = 0.f;

        for (int kc = 0; kc < 32; ++kc) {
            // prefetch stage (issued before barrier; latency hidden by other block)
            float4 st[4];
            #pragma unroll
            for (int i = 0; i < 4; ++i)
                st[i] = cbq[(size_t)(kc * 2 + qloc) * QN + chunk * 512 + cidx + 128 * i];
            __syncthreads();   // prior compute done reading Cs (and pass 0: Ts published)
            #pragma unroll
            for (int i = 0; i < 4; ++i)
                Cs[qloc][cidx + 128 * i] = st[i];   // lane-contiguous b128 writes
            __syncthreads();

            #pragma unroll
            for (int kq = 0; kq < 2; ++kq) {
                float4 tv[6];
                #pragma unroll
                for (int u = 0; u < 6; ++u)       // wave-broadcast reads (2 addrs/wave)
                    tv[u] = *(const float4*)&Ts[(tg + 8*u) * TSTR2 + kc * 8 + kq * 4];
                #pragma unroll
                for (int j = 0; j < 16; ++j) {
                    float4 cv = Cs[kq][cg + 32*j]; // lane-contiguous b128 reads
                    #pragma unroll
                    for (int u = 0; u < 6; ++u) {
                        acc[u][j] += tv[u].x * cv.x;
                        acc[u][j] += tv[u].y * cv.y;
                        acc[u][j] += tv[u].z * cv.z;
                        acc[u][j] += tv[u].w * cv.w;
                    }
                }
            }
        }
        // fold chunk (ascending code index, strict > : first-max tie-break)
        #pragma unroll
        for (int j = 0; j < 16; ++j) {
            int code = chunk * 512 + 32 * j + cg;
            #pragma unroll
            for (int u = 0; u < 6; ++u) {
                if (acc[u][j] > best[u]) { best[u] = acc[u][j]; bidx[u] = code; }
            }
        }
    }

    // ---- reduce across the 32 code-lanes of each half-wave ----
    #pragma unroll
    for (int off = 16; off > 0; off >>= 1) {
        #pragma unroll
        for (int u = 0; u < 6; ++u) {
            float ov = __shfl_down(best[u], off);
            int   oi = __shfl_down(bidx[u], off);
            if (ov > best[u] || (ov == best[u] && oi < bidx[u])) {
                best[u] = ov; bidx[u] = oi;
            }
        }
    }
    if (cg == 0) {
        #pragma unroll
        for (int u = 0; u < 6; ++u) {
            int tk = n0 + tg + 8*u;
            if (tk < NTOK) out[tk] = bidx[u];
        }
    }
}

extern "C" void kernel_launch(void* const* d_in, const int* in_sizes, int n_in,
                              void* d_out, int out_size, void* d_ws, size_t ws_size,
                              hipStream_t stream) {
    const float* fbank = (const float*)d_in[0];   // 16 x 8192 x 128
    const float* convw = (const float*)d_in[1];   // 512 x 1 x 16 x 16
    const float* proj  = (const float*)d_in[2];   // 512 x 256
    const float* cbook = (const float*)d_in[3];   // 1024 x 256
    int* out = (int*)d_out;                       // 65536 int32

    char* ws = (char*)d_ws;
    float4* cbq  = (float4*)ws;                             // 1 MB quad-interleaved codebook
    float*  projT = (float*)(ws + (1u << 20));              // 512 KB
    float*  tws   = (float*)(ws + (1u << 20) + (1u << 19)); // 64 MB

    hipLaunchKernelGGL(k_cbnorm,    dim3(QN),            dim3(64),  0, stream, cbook, cbq);
    hipLaunchKernelGGL(k_transpose, dim3(ED * QD / 256), dim3(256), 0, stream, proj, projT);
    hipLaunchKernelGGL(k_feat,      dim3(NTOK / 16),     dim3(256), 0, stream, fbank, convw, projT, tws);
    hipLaunchKernelGGL(k_argmax,    dim3((NTOK + ATOK - 1) / ATOK), dim3(256), 0, stream, tws, cbq, out);
}

// Round 5
// 913.521 us; speedup vs baseline: 2.9085x; 1.5218x over previous
//
#include <hip/hip_runtime.h>
#include <math.h>

#define TB 16
#define TT 8192
#define TM 128
#define ED 512     // EMBED_DIM
#define QD 256     // QUANT_DIM
#define QN 1024    // QUANT_N
#define NTOK 65536

// ---------------- kernel 1: codebook l2-normalize -> quad-interleaved cbq ----------------
// cbq layout: [QD/4 quads][QN codes][4 floats]; lane's float4 IS its k-quad.
__global__ __launch_bounds__(64) void k_cbnorm(const float* __restrict__ cb,
                                               float4* __restrict__ cbq) {
    int k = blockIdx.x;
    int lane = threadIdx.x;               // 64 lanes, one k-quad each
    float4 v = ((const float4*)(cb + (size_t)k * QD))[lane];
    float ss = v.x*v.x + v.y*v.y + v.z*v.z + v.w*v.w;
    #pragma unroll
    for (int off = 32; off > 0; off >>= 1) ss += __shfl_down(ss, off);
    ss = __shfl(ss, 0);
    float inv = 1.0f / fmaxf(sqrtf(ss), 1e-12f);
    float4 o; o.x = v.x*inv; o.y = v.y*inv; o.z = v.z*inv; o.w = v.w*inv;
    cbq[(size_t)lane * QN + k] = o;
}

// ---------------- kernel 2: precompute M2 = [Wt@P | Wt@W] (quad-interleaved), wsum, p1 ----
// col < 256 : M[k][col] = sum_d convw[d][k] * proj[d][col]
// col >= 256: G[k][col-256] = sum_d convw[d][k] * convw[d][col-256]
// m2q[kq*512 + col] = float4(M2[col][4kq..4kq+3])   (k quads)
__global__ __launch_bounds__(256) void k_prep(const float* __restrict__ convw,
                                              const float* __restrict__ proj,
                                              float4* __restrict__ m2q,
                                              float* __restrict__ wsum,
                                              float* __restrict__ p1) {
    int col = blockIdx.x;
    int t = threadIdx.x;
    if (col < 512) {
        __shared__ float colv[512];
        const float* src = (col < 256) ? (proj + col) : (convw + (col - 256));
        colv[t]       = src[(size_t)t * 256];
        colv[t + 256] = src[(size_t)(t + 256) * 256];
        __syncthreads();
        float acc = 0.f;
        for (int d = 0; d < 512; ++d)
            acc += convw[d * 256 + t] * colv[d];
        float* dst = (float*)&m2q[(size_t)(t >> 2) * 512 + col];
        dst[t & 3] = acc;
    } else if (col == 512) {
        float s = 0.f;
        for (int d = 0; d < 512; ++d) s += convw[d * 256 + t];
        wsum[t] = s;
    } else {
        float s = 0.f;
        for (int d = 0; d < 512; ++d) s += proj[d * 256 + t];
        p1[t] = s;
    }
}

// ---------------- kernel 3: fused patch-GEMM + LN epilogue -> t[65536][256] ----------------
// Per token: v[0..511] = patch @ [M|G]; mu = patch.wsum/512;
// sumsq = v[256..511] . patch; rs = rsqrt(sumsq/512 - mu^2 + eps);
// t[q] = rs*(v[q] - mu*p1[q]).
#define ATOK 48
#define TSTR2 260

__global__ __launch_bounds__(256, 2) void k_tok(const float* __restrict__ fbank,
                                                const float4* __restrict__ m2q,
                                                const float* __restrict__ wsum,
                                                const float* __restrict__ p1,
                                                float* __restrict__ tws) {
    __shared__ float  Ts[ATOK * TSTR2];   // 49.9 KB: 48 patches x 256
    __shared__ float4 Cs[2][512];         // 16 KB: [k-quad][col][4]
    __shared__ float  wsS[256], p1S[256];

    int tid = threadIdx.x;
    int n0 = blockIdx.x * ATOK;

    wsS[tid] = wsum[tid];
    p1S[tid] = p1[tid];

    // ---- stage 48 patches: 768 segments of 16 floats; 3 segments/thread ----
    #pragma unroll
    for (int i = 0; i < 3; ++i) {
        int s = tid + 256 * i;           // 0..767
        int j = s >> 4, ph = s & 15;
        int n = n0 + j; if (n > NTOK - 1) n = NTOK - 1;
        int b = n >> 12, r = n & 4095, h = r >> 3, w = r & 7;
        const float4* src = (const float4*)(fbank + ((size_t)(b * TT + h * 16 + ph)) * TM + w * 16);
        float4* dst = (float4*)&Ts[j * TSTR2 + ph * 16];
        #pragma unroll
        for (int c = 0; c < 4; ++c) dst[c] = src[c];
    }

    int tg = tid >> 5;       // 0..7: tokens {tg + 8u, u=0..5}
    int cg = tid & 31;       // cols {cg + 32j, j=0..15}
    int qloc = tid >> 7;     // staging k-quad
    int cidx = tid & 127;    // staging col base

    float acc[6][16];
    #pragma unroll
    for (int u = 0; u < 6; ++u)
        #pragma unroll
        for (int j = 0; j < 16; ++j) acc[u][j] = 0.f;

    for (int kc = 0; kc < 32; ++kc) {
        float4 st[4];
        #pragma unroll
        for (int i = 0; i < 4; ++i)
            st[i] = m2q[(size_t)(kc * 2 + qloc) * 512 + cidx + 128 * i];
        __syncthreads();   // prior compute done with Cs (kc=0: publishes Ts/wsS/p1S)
        #pragma unroll
        for (int i = 0; i < 4; ++i)
            Cs[qloc][cidx + 128 * i] = st[i];
        __syncthreads();

        #pragma unroll
        for (int kq = 0; kq < 2; ++kq) {
            float4 tv[6];
            #pragma unroll
            for (int u = 0; u < 6; ++u)       // wave-broadcast reads
                tv[u] = *(const float4*)&Ts[(tg + 8*u) * TSTR2 + kc * 8 + kq * 4];
            #pragma unroll
            for (int j = 0; j < 16; ++j) {
                float4 cv = Cs[kq][cg + 32*j]; // lane-contiguous b128 reads
                #pragma unroll
                for (int u = 0; u < 6; ++u) {
                    acc[u][j] += tv[u].x * cv.x;
                    acc[u][j] += tv[u].y * cv.y;
                    acc[u][j] += tv[u].z * cv.z;
                    acc[u][j] += tv[u].w * cv.w;
                }
            }
        }
    }

    // ---- epilogue: per-token mu / sumsq via half-wave reduction ----
    float part_sq[6], part_mu[6];
    #pragma unroll
    for (int u = 0; u < 6; ++u) {
        const float* trow = &Ts[(tg + 8*u) * TSTR2];
        float sq = 0.f;
        #pragma unroll
        for (int j = 8; j < 16; ++j)          // G-part cols: c = 32*(j-8)+cg
            sq += acc[u][j] * trow[32 * (j - 8) + cg];
        float pm = 0.f;
        #pragma unroll
        for (int z = 0; z < 8; ++z) {         // k = cg + 32z: lane-consecutive, conflict-free
            int k = cg + 32 * z;
            pm += trow[k] * wsS[k];
        }
        part_sq[u] = sq; part_mu[u] = pm;
    }
    #pragma unroll
    for (int off = 16; off > 0; off >>= 1) {
        #pragma unroll
        for (int u = 0; u < 6; ++u) {
            part_sq[u] += __shfl_down(part_sq[u], off);
            part_mu[u] += __shfl_down(part_mu[u], off);
        }
    }
    int base = (tid & 63) & 32;               // lane 0 / 32 holds each half-wave's sum
    float mu[6], rs[6];
    #pragma unroll
    for (int u = 0; u < 6; ++u) {
        float sq = __shfl(part_sq[u], base);
        float pm = __shfl(part_mu[u], base);
        float m = pm * (1.0f / 512.0f);
        float v = sq * (1.0f / 512.0f) - m * m;
        mu[u] = m;
        rs[u] = rsqrtf(v + 1e-5f);            // positive scale: argmax-neutral
    }

    // ---- write t ----
    #pragma unroll
    for (int u = 0; u < 6; ++u) {
        int tk = n0 + tg + 8*u;
        if (tk < NTOK) {
            #pragma unroll
            for (int j = 0; j < 8; ++j) {
                int q = 32 * j + cg;
                tws[(size_t)tk * QD + q] = rs[u] * (acc[u][j] - mu[u] * p1S[q]);
            }
        }
    }
}

// ---------------- kernel 4: sim = t @ cbn^T, argmax over 1024 codes ----------------
__global__ __launch_bounds__(256, 2) void k_argmax(const float* __restrict__ tws,
                                                   const float4* __restrict__ cbq,
                                                   int* __restrict__ out) {
    __shared__ float  Ts[ATOK * TSTR2];   // 49.9 KB
    __shared__ float4 Cs[2][512];         // 16 KB

    int tid = threadIdx.x;
    int n0 = blockIdx.x * ATOK;

    // ---- stage Ts: 48 rows x 64 float4 = 3072 float4; 12 per thread ----
    {
        const float4* twsf4 = (const float4*)tws;
        #pragma unroll
        for (int i = 0; i < 12; ++i) {
            int ft = tid + 256 * i;
            int row = ft >> 6, col = ft & 63;
            int grow = n0 + row; if (grow > NTOK - 1) grow = NTOK - 1;
            float4 v = twsf4[(size_t)grow * (QD/4) + col];
            *(float4*)&Ts[row * TSTR2 + col * 4] = v;
        }
    }

    int tg = tid >> 5;
    int cg = tid & 31;
    int qloc = tid >> 7;
    int cidx = tid & 127;

    float best[6]; int bidx[6];
    #pragma unroll
    for (int u = 0; u < 6; ++u) { best[u] = -3.4e38f; bidx[u] = 0; }

    for (int chunk = 0; chunk < 2; ++chunk) {
        float acc[6][16];
        #pragma unroll
        for (int u = 0; u < 6; ++u)
            #pragma unroll
            for (int j = 0; j < 16; ++j) acc[u][j] = 0.f;

        for (int kc = 0; kc < 32; ++kc) {
            float4 st[4];
            #pragma unroll
            for (int i = 0; i < 4; ++i)
                st[i] = cbq[(size_t)(kc * 2 + qloc) * QN + chunk * 512 + cidx + 128 * i];
            __syncthreads();
            #pragma unroll
            for (int i = 0; i < 4; ++i)
                Cs[qloc][cidx + 128 * i] = st[i];
            __syncthreads();

            #pragma unroll
            for (int kq = 0; kq < 2; ++kq) {
                float4 tv[6];
                #pragma unroll
                for (int u = 0; u < 6; ++u)
                    tv[u] = *(const float4*)&Ts[(tg + 8*u) * TSTR2 + kc * 8 + kq * 4];
                #pragma unroll
                for (int j = 0; j < 16; ++j) {
                    float4 cv = Cs[kq][cg + 32*j];
                    #pragma unroll
                    for (int u = 0; u < 6; ++u) {
                        acc[u][j] += tv[u].x * cv.x;
                        acc[u][j] += tv[u].y * cv.y;
                        acc[u][j] += tv[u].z * cv.z;
                        acc[u][j] += tv[u].w * cv.w;
                    }
                }
            }
        }
        #pragma unroll
        for (int j = 0; j < 16; ++j) {
            int code = chunk * 512 + 32 * j + cg;
            #pragma unroll
            for (int u = 0; u < 6; ++u) {
                if (acc[u][j] > best[u]) { best[u] = acc[u][j]; bidx[u] = code; }
            }
        }
    }

    #pragma unroll
    for (int off = 16; off > 0; off >>= 1) {
        #pragma unroll
        for (int u = 0; u < 6; ++u) {
            float ov = __shfl_down(best[u], off);
            int   oi = __shfl_down(bidx[u], off);
            if (ov > best[u] || (ov == best[u] && oi < bidx[u])) {
                best[u] = ov; bidx[u] = oi;
            }
        }
    }
    if (cg == 0) {
        #pragma unroll
        for (int u = 0; u < 6; ++u) {
            int tk = n0 + tg + 8*u;
            if (tk < NTOK) out[tk] = bidx[u];
        }
    }
}

extern "C" void kernel_launch(void* const* d_in, const int* in_sizes, int n_in,
                              void* d_out, int out_size, void* d_ws, size_t ws_size,
                              hipStream_t stream) {
    const float* fbank = (const float*)d_in[0];   // 16 x 8192 x 128
    const float* convw = (const float*)d_in[1];   // 512 x 1 x 16 x 16 (= [512][256])
    const float* proj  = (const float*)d_in[2];   // 512 x 256
    const float* cbook = (const float*)d_in[3];   // 1024 x 256
    int* out = (int*)d_out;                       // 65536 int32

    char* ws = (char*)d_ws;
    float4* cbq  = (float4*)ws;                              // 1 MB
    float4* m2q  = (float4*)(ws + (1u << 20));               // 512 KB
    float*  wsum = (float*)(ws + (1u << 20) + (1u << 19));   // 1 KB
    float*  p1   = (float*)(ws + (1u << 20) + (1u << 19) + 4096);
    float*  tws  = (float*)(ws + (1u << 20) + (1u << 19) + 8192);  // 64 MB

    hipLaunchKernelGGL(k_cbnorm, dim3(QN),  dim3(64),  0, stream, cbook, cbq);
    hipLaunchKernelGGL(k_prep,   dim3(514), dim3(256), 0, stream, convw, proj, m2q, wsum, p1);
    hipLaunchKernelGGL(k_tok,    dim3((NTOK + ATOK - 1) / ATOK), dim3(256), 0, stream,
                       fbank, m2q, wsum, p1, tws);
    hipLaunchKernelGGL(k_argmax, dim3((NTOK + ATOK - 1) / ATOK), dim3(256), 0, stream,
                       tws, cbq, out);
}